// Round 5
// baseline (562.018 us; speedup 1.0000x reference)
//
#include <hip/hip_runtime.h>
#include <cstdint>
#include <cstddef>

#define S_LEN 2048
#define BATCH 2
#define EMB   1024
#define NHEAD 16
#define HDIM  64

typedef short short8 __attribute__((ext_vector_type(8)));   // 8 bf16 (4 VGPRs)
typedef float f32x4  __attribute__((ext_vector_type(4)));

__device__ __forceinline__ unsigned short f2b(float f) {
    unsigned int u = __float_as_uint(f);
    u = (u + 0x7FFFu + ((u >> 16) & 1u)) >> 16;   // RNE
    return (unsigned short)u;
}
__device__ __forceinline__ unsigned int pk2(float a, float b) {
    return (unsigned int)f2b(a) | ((unsigned int)f2b(b) << 16);
}
__device__ __forceinline__ float b2f_lo(unsigned int u) { return __uint_as_float(u << 16); }
__device__ __forceinline__ float b2f_hi(unsigned int u) { return __uint_as_float(u & 0xFFFF0000u); }

// ---------------------------------------------------------------------------
// GEMM body: C[M,N] = A[M,K] @ W[N,K]^T + bias. Tile 64(M)x128(N), Ktile=32,
// 512 threads / 8 waves (wave grid 2x4, each wave 32x32 = 2x2 MFMA tiles).
// Double-buffered LDS, register prefetch, 1 barrier per K-tile.
// mode 0: fp32 out[r*EMB+n]
// mode 1: bf16 out[((b*16+h)*S+s)*64+d]   (head-split)
// mode 2: bf16 out[((b*16+h)*64+d)*S+s]   (v transposed per head)
// ---------------------------------------------------------------------------
template<int ABF16>
__device__ __forceinline__ void gemm_body(
    ushort (*As)[64 * 40], ushort (*Bs)[128 * 40],
    const void* __restrict__ A_, const float* __restrict__ W,
    const float* __restrict__ bias, void* __restrict__ out_,
    float scale, int mode)
{
    constexpr int K = EMB;
    constexpr int NT = K / 32;
    constexpr int LDP = 40;

    const int t    = threadIdx.x;
    const int lane = t & 63;
    const int wave = t >> 6;
    const int quad = lane >> 4;
    const int l15  = lane & 15;
    const int wm   = wave >> 2;          // 0..1
    const int wn   = wave & 3;           // 0..3
    const int m0   = blockIdx.x * 64;
    const int n0   = blockIdx.y * 128;

    const int rowA = t >> 3, ka = (t & 7) * 4;   // A: 64 rows x 32k, 4 u16/thr
    const int rowW = t >> 2, kw = (t & 3) * 8;   // W: 128 rows x 32k, 8 u16/thr

    const float*  Af  = (const float*)A_;
    const ushort* Ab  = (const ushort*)A_;
    const size_t aOff = (size_t)(m0 + rowA) * K + ka;
    const float*  Wp  = W + (size_t)(n0 + rowW) * K + kw;

    f32x4 acc[2][2];
#pragma unroll
    for (int mi = 0; mi < 2; ++mi)
#pragma unroll
        for (int ni = 0; ni < 2; ++ni) acc[mi][ni] = (f32x4){0.f, 0.f, 0.f, 0.f};

    uint2 ua;
    uint4 uw;
    // prologue: tile 0
    if (ABF16) ua = *(const uint2*)(Ab + aOff);
    else {
        float4 f = *(const float4*)(Af + aOff);
        ua = make_uint2(pk2(f.x, f.y), pk2(f.z, f.w));
    }
    {
        float4 g0 = *(const float4*)(Wp);
        float4 g1 = *(const float4*)(Wp + 4);
        uw = make_uint4(pk2(g0.x,g0.y), pk2(g0.z,g0.w), pk2(g1.x,g1.y), pk2(g1.z,g1.w));
    }
    *(uint2*)&As[0][rowA * LDP + ka] = ua;
    *(uint4*)&Bs[0][rowW * LDP + kw] = uw;
    __syncthreads();

    for (int kt = 0; kt < NT; ++kt) {
        const int cur = kt & 1;
        if (kt + 1 < NT) {
            const int k0 = (kt + 1) * 32;
            if (ABF16) ua = *(const uint2*)(Ab + aOff + k0);
            else {
                float4 f = *(const float4*)(Af + aOff + k0);
                ua = make_uint2(pk2(f.x, f.y), pk2(f.z, f.w));
            }
            float4 g0 = *(const float4*)(Wp + k0);
            float4 g1 = *(const float4*)(Wp + k0 + 4);
            uw = make_uint4(pk2(g0.x,g0.y), pk2(g0.z,g0.w), pk2(g1.x,g1.y), pk2(g1.z,g1.w));
        }
        short8 af[2], bf[2];
#pragma unroll
        for (int mi = 0; mi < 2; ++mi)
            af[mi] = *(const short8*)&As[cur][(wm * 32 + mi * 16 + l15) * LDP + quad * 8];
#pragma unroll
        for (int ni = 0; ni < 2; ++ni)
            bf[ni] = *(const short8*)&Bs[cur][(wn * 32 + ni * 16 + l15) * LDP + quad * 8];
#pragma unroll
        for (int mi = 0; mi < 2; ++mi)
#pragma unroll
            for (int ni = 0; ni < 2; ++ni)
                acc[mi][ni] = __builtin_amdgcn_mfma_f32_16x16x32_bf16(
                    af[mi], bf[ni], acc[mi][ni], 0, 0, 0);
        if (kt + 1 < NT) {
            const int nxt = (kt + 1) & 1;
            *(uint2*)&As[nxt][rowA * LDP + ka] = ua;
            *(uint4*)&Bs[nxt][rowW * LDP + kw] = uw;
            __syncthreads();
        }
    }

    // epilogue: D[row=quad*4+r][col=l15] per 16x16 tile
#pragma unroll
    for (int mi = 0; mi < 2; ++mi)
#pragma unroll
        for (int ni = 0; ni < 2; ++ni) {
            const int col = n0 + wn * 32 + ni * 16 + l15;
            const float bc = bias[col];
#pragma unroll
            for (int r = 0; r < 4; ++r) {
                const int rg = m0 + wm * 32 + mi * 16 + quad * 4 + r;
                const float v = (acc[mi][ni][r] + bc) * scale;
                if (mode == 0) {
                    ((float*)out_)[(size_t)rg * EMB + col] = v;
                } else {
                    const int s  = rg >> 1;
                    const int bb = rg & 1;
                    const int h  = col >> 6;
                    const int d  = col & 63;
                    if (mode == 1)
                        ((ushort*)out_)[(((size_t)(bb * NHEAD + h)) * S_LEN + s) * HDIM + d] = f2b(v);
                    else
                        ((ushort*)out_)[(((size_t)(bb * NHEAD + h)) * HDIM + d) * S_LEN + s] = f2b(v);
                }
            }
        }
}

// Fused QKV projections: blockIdx.z in {0,1,2} selects q/k/v. 1536 blocks.
// launch_bounds(512,4): cap total regs (VGPR+AGPR unified file) at 128 ->
// 4 waves/SIMD. Live set ~70 regs, no spill risk.
__global__ __launch_bounds__(512, 4)
void gemm_qkv(const float* __restrict__ qi, const float* __restrict__ ki,
              const float* __restrict__ vi,
              const float* __restrict__ qW, const float* __restrict__ kW,
              const float* __restrict__ vW,
              const float* __restrict__ qB, const float* __restrict__ kB,
              const float* __restrict__ vB,
              ushort* __restrict__ qO, ushort* __restrict__ kO,
              ushort* __restrict__ vO)
{
    __shared__ ushort As[2][64 * 40];
    __shared__ ushort Bs[2][128 * 40];
    const int z = blockIdx.z;
    const float* A    = (z == 0) ? qi : (z == 1) ? ki : vi;
    const float* W    = (z == 0) ? qW : (z == 1) ? kW : vW;
    const float* bias = (z == 0) ? qB : (z == 1) ? kB : vB;
    ushort* out       = (z == 0) ? qO : (z == 1) ? kO : vO;
    const float scale = (z == 0) ? 0.125f : 1.0f;
    const int   mode  = (z == 2) ? 2 : 1;
    gemm_body<0>(As, Bs, A, W, bias, out, scale, mode);
}

// Output projection: fp32 out, bf16 A.
__global__ __launch_bounds__(512, 4)
void gemm_z(const ushort* __restrict__ A, const float* __restrict__ W,
            const float* __restrict__ bias, float* __restrict__ out)
{
    __shared__ ushort As[2][64 * 40];
    __shared__ ushort Bs[2][128 * 40];
    gemm_body<1>(As, Bs, A, W, bias, out, 1.0f, 0);
}

// ---------------------------------------------------------------------------
// Fused attention. Block = (16 q-rows, b, head-group g). 512 thr / 8 waves,
// 512 blocks. Heads h = g*8..g*8+7 looped.
// Shift-softmax exp(s-8): shift-invariant, scores ~N(0,0.33), no overflow.
// Score e-values go straight to LDS (bf16); pavg is accumulated by re-reading
// them vectorized after the sum barrier -> no sc[16] register array.
// launch_bounds(512,4): R4 ran at 2 waves/SIMD (Occ 23%) because the unified
// VGPR+AGPR total exceeded 128 (VGPR_Count=116 excludes AGPRs). Live set
// without the e-array is ~105-115 -> fits the 128 cap, doubling occupancy.
// (R3's spill came from the 64-reg e-array under the same cap, removed in R4.)
// ---------------------------------------------------------------------------
#define PLD 2056   // 2048 + 8 pad (ushorts)
__global__ __launch_bounds__(512, 4)
void attn_bf16(const ushort* __restrict__ qw, const ushort* __restrict__ kw,
               const ushort* __restrict__ vt, ushort* __restrict__ ao,
               ushort* __restrict__ pavg_ws)
{
    __shared__ ushort pLds[16 * PLD];      // 65792 B (unnormalized e, bf16)
    __shared__ float  redS[8 * 16];        // per-wave row-sum partials
    __shared__ float  red2[4 * 16 * 16];   // PV khalf partials

    const int t     = threadIdx.x;
    const int lane  = t & 63;
    const int wave  = t >> 6;              // 0..7
    const int quad  = lane >> 4;
    const int l15   = lane & 15;
    const int rbase = quad * 4;
    const int sq0   = blockIdx.x * 16;
    const int b     = blockIdx.y;
    const int g     = blockIdx.z;          // head group
    const int ntile = wave & 3;            // PV d-tile
    const int khalf = wave >> 2;           // PV k-half
    // pavg ownership: rows rbase+r, 16 cols starting at colAvg
    const int colAvg = (wave * 16 + l15) * 16;

    float pavg[4][16];
#pragma unroll
    for (int r = 0; r < 4; ++r)
#pragma unroll
        for (int j = 0; j < 16; ++j) pavg[r][j] = 0.f;

    for (int hh = 0; hh < 8; ++hh) {
        const int h  = g * 8 + hh;
        const int bh = b * NHEAD + h;
        const ushort* qbase = qw + ((size_t)bh * S_LEN + sq0) * HDIM;
        const ushort* kbse  = kw + (size_t)bh * S_LEN * HDIM;

        const short8 qf0 = *(const short8*)(qbase + l15 * HDIM + quad * 8);
        const short8 qf1 = *(const short8*)(qbase + l15 * HDIM + 32 + quad * 8);

        // ---- scores + exp + stage (wave owns cols [wave*256, wave*256+256)) ----
        float s4[4] = {0.f, 0.f, 0.f, 0.f};
#pragma unroll 4
        for (int ti = 0; ti < 16; ++ti) {
            const int c0 = wave * 256 + ti * 16;
            const ushort* kr = kbse + (size_t)(c0 + l15) * HDIM;
            const short8 k0 = *(const short8*)(kr + quad * 8);
            const short8 k1 = *(const short8*)(kr + 32 + quad * 8);
            f32x4 a = (f32x4){0.f, 0.f, 0.f, 0.f};
            a = __builtin_amdgcn_mfma_f32_16x16x32_bf16(qf0, k0, a, 0, 0, 0);
            a = __builtin_amdgcn_mfma_f32_16x16x32_bf16(qf1, k1, a, 0, 0, 0);
#pragma unroll
            for (int r = 0; r < 4; ++r) {
                // exp(s - 8) = exp2(s*log2e - 8*log2e)
                const float e = exp2f(fmaf(a[r], 1.44269504f, -11.54156035f));
                s4[r] += e;
                pLds[(rbase + r) * PLD + c0 + l15] = f2b(e);
            }
        }
        // wave-level row-sum over its 256 cols
#pragma unroll
        for (int off = 1; off < 16; off <<= 1)
#pragma unroll
            for (int r = 0; r < 4; ++r) s4[r] += __shfl_xor(s4[r], off, 16);
        if (l15 == 0)
#pragma unroll
            for (int r = 0; r < 4; ++r) redS[wave * 16 + rbase + r] = s4[r];
        __syncthreads();                                        // B1

        float rinv[4];
#pragma unroll
        for (int r = 0; r < 4; ++r) {
            float s = redS[rbase + r];
#pragma unroll
            for (int w = 1; w < 8; ++w) s += redS[w * 16 + rbase + r];
            rinv[r] = 1.0f / s;
        }

        // ---- pavg accumulation: re-read bf16 e vectorized from LDS ----
#pragma unroll
        for (int r = 0; r < 4; ++r) {
            const float ri = rinv[r];
#pragma unroll
            for (int c = 0; c < 2; ++c) {
                const uint4 u = *(const uint4*)&pLds[(rbase + r) * PLD + colAvg + c * 8];
                pavg[r][c * 8 + 0] = fmaf(b2f_lo(u.x), ri, pavg[r][c * 8 + 0]);
                pavg[r][c * 8 + 1] = fmaf(b2f_hi(u.x), ri, pavg[r][c * 8 + 1]);
                pavg[r][c * 8 + 2] = fmaf(b2f_lo(u.y), ri, pavg[r][c * 8 + 2]);
                pavg[r][c * 8 + 3] = fmaf(b2f_hi(u.y), ri, pavg[r][c * 8 + 3]);
                pavg[r][c * 8 + 4] = fmaf(b2f_lo(u.z), ri, pavg[r][c * 8 + 4]);
                pavg[r][c * 8 + 5] = fmaf(b2f_hi(u.z), ri, pavg[r][c * 8 + 5]);
                pavg[r][c * 8 + 6] = fmaf(b2f_lo(u.w), ri, pavg[r][c * 8 + 6]);
                pavg[r][c * 8 + 7] = fmaf(b2f_hi(u.w), ri, pavg[r][c * 8 + 7]);
            }
        }

        // ---- PV on unnormalized e; scale by rinv at the end ----
        const ushort* vrow = vt + ((size_t)bh * HDIM + ntile * 16 + l15) * S_LEN + khalf * 1024;
        const ushort* prow = &pLds[l15 * PLD + khalf * 1024];
        f32x4 o0 = (f32x4){0.f, 0.f, 0.f, 0.f}, o1 = o0;
#pragma unroll 8
        for (int st = 0; st < 32; st += 2) {
            const short8 pa0 = *(const short8*)(prow + st * 32 + quad * 8);
            const short8 vb0 = *(const short8*)(vrow + st * 32 + quad * 8);
            o0 = __builtin_amdgcn_mfma_f32_16x16x32_bf16(pa0, vb0, o0, 0, 0, 0);
            const short8 pa1 = *(const short8*)(prow + (st + 1) * 32 + quad * 8);
            const short8 vb1 = *(const short8*)(vrow + (st + 1) * 32 + quad * 8);
            o1 = __builtin_amdgcn_mfma_f32_16x16x32_bf16(pa1, vb1, o1, 0, 0, 0);
        }
        const f32x4 o = o0 + o1;
        if (khalf == 1) {
#pragma unroll
            for (int r = 0; r < 4; ++r)
                red2[ntile * 256 + (rbase + r) * 16 + l15] = o[r];
        }
        __syncthreads();                                        // B2
        if (khalf == 0) {
#pragma unroll
            for (int r = 0; r < 4; ++r) {
                const float val = (o[r] + red2[ntile * 256 + (rbase + r) * 16 + l15]) * rinv[r];
                const int s = sq0 + rbase + r;
                const int d = ntile * 16 + l15;
                ao[((size_t)s * BATCH + b) * EMB + h * HDIM + d] = f2b(val);
            }
        }
    }

    // ---- write attn_avg partial (already /16), 16B packed stores ----
    const float inv16 = 0.0625f;
#pragma unroll
    for (int r = 0; r < 4; ++r) {
        const int s = sq0 + rbase + r;
        ushort* dst = pavg_ws + (((size_t)(g * BATCH + b)) * S_LEN + s) * S_LEN + colAvg;
#pragma unroll
        for (int c = 0; c < 2; ++c) {
            uint4 u;
            u.x = pk2(pavg[r][c * 8 + 0] * inv16, pavg[r][c * 8 + 1] * inv16);
            u.y = pk2(pavg[r][c * 8 + 2] * inv16, pavg[r][c * 8 + 3] * inv16);
            u.z = pk2(pavg[r][c * 8 + 4] * inv16, pavg[r][c * 8 + 5] * inv16);
            u.w = pk2(pavg[r][c * 8 + 6] * inv16, pavg[r][c * 8 + 7] * inv16);
            *(uint4*)(dst + c * 8) = u;
        }
    }
}

// ---------------------------------------------------------------------------
// attn_avg = partial[g=0] + partial[g=1]  (bf16 -> fp32)
// ---------------------------------------------------------------------------
__global__ __launch_bounds__(256)
void avg_reduce(const ushort* __restrict__ p, float* __restrict__ out)
{
    const size_t N = (size_t)BATCH * S_LEN * S_LEN;          // 8,388,608
    const size_t i = ((size_t)blockIdx.x * 256 + threadIdx.x) * 8;
    const uint4 a = *(const uint4*)(p + i);
    const uint4 c = *(const uint4*)(p + i + N);
    float4 o0 = make_float4(b2f_lo(a.x) + b2f_lo(c.x), b2f_hi(a.x) + b2f_hi(c.x),
                            b2f_lo(a.y) + b2f_lo(c.y), b2f_hi(a.y) + b2f_hi(c.y));
    float4 o1 = make_float4(b2f_lo(a.z) + b2f_lo(c.z), b2f_hi(a.z) + b2f_hi(c.z),
                            b2f_lo(a.w) + b2f_lo(c.w), b2f_hi(a.w) + b2f_hi(c.w));
    *(float4*)(out + i)     = o0;
    *(float4*)(out + i + 4) = o1;
}

// ---------------------------------------------------------------------------
extern "C" void kernel_launch(void* const* d_in, const int* in_sizes, int n_in,
                              void* d_out, int out_size, void* d_ws, size_t ws_size,
                              hipStream_t stream)
{
    const float* query = (const float*)d_in[0];
    const float* key   = (const float*)d_in[1];
    const float* value = (const float*)d_in[2];
    const float* q_w   = (const float*)d_in[3];
    const float* q_b   = (const float*)d_in[4];
    const float* k_w   = (const float*)d_in[5];
    const float* k_b   = (const float*)d_in[6];
    const float* v_w   = (const float*)d_in[7];
    const float* v_b   = (const float*)d_in[8];
    const float* out_w = (const float*)d_in[9];
    const float* out_b = (const float*)d_in[10];

    float* Z        = (float*)d_out;                       // [S,B,E] fp32
    float* attn_avg = Z + (size_t)S_LEN * BATCH * EMB;     // [B,S,S] fp32

    const size_t QKV = (size_t)S_LEN * BATCH * EMB;        // 4,194,304
    ushort* q_ws  = (ushort*)d_ws;                         // bf16 [B*H][S][D]
    ushort* k_ws  = q_ws + QKV;                            // bf16 [B*H][S][D]
    ushort* vt_ws = k_ws + QKV;                            // bf16 [B*H][D][S]
    ushort* ao_ws = vt_ws + QKV;                           // bf16 [S][B][E]
    ushort* pavg_ws = ao_ws + QKV;                         // bf16 [2][B][S][S]

    const dim3 blkG(512);
    const dim3 gq(64, 8, 3);                               // M/64 x N/128 x {q,k,v}
    gemm_qkv<<<gq, blkG, 0, stream>>>(query, key, value, q_w, k_w, v_w,
                                      q_b, k_b, v_b, q_ws, k_ws, vt_ws);

    const dim3 ga(S_LEN / 16, BATCH, 2);                   // 512 blocks
    attn_bf16<<<ga, blkG, 0, stream>>>(q_ws, k_ws, vt_ws, ao_ws, pavg_ws);

    avg_reduce<<<4096, 256, 0, stream>>>(pavg_ws, attn_avg);

    const dim3 gz(64, 8);
    gemm_z<<<gz, blkG, 0, stream>>>(ao_ws, out_w, out_b, Z);
}

// Round 6
// 496.036 us; speedup vs baseline: 1.1330x; 1.1330x over previous
//
#include <hip/hip_runtime.h>
#include <cstdint>
#include <cstddef>

#define S_LEN 2048
#define BATCH 2
#define EMB   1024
#define NHEAD 16
#define HDIM  64

typedef short short8 __attribute__((ext_vector_type(8)));   // 8 bf16 (4 VGPRs)
typedef float f32x4  __attribute__((ext_vector_type(4)));

__device__ __forceinline__ unsigned short f2b(float f) {
    unsigned int u = __float_as_uint(f);
    u = (u + 0x7FFFu + ((u >> 16) & 1u)) >> 16;   // RNE
    return (unsigned short)u;
}
__device__ __forceinline__ unsigned int pk2(float a, float b) {
    return (unsigned int)f2b(a) | ((unsigned int)f2b(b) << 16);
}
// fast round (half-away): 2 ops, used in attn hot paths
__device__ __forceinline__ unsigned short f2bf(float f) {
    return (unsigned short)((__float_as_uint(f) + 0x8000u) >> 16);
}
__device__ __forceinline__ unsigned int pk2f(float a, float b) {
    return ((__float_as_uint(a) + 0x8000u) >> 16) |
           ((__float_as_uint(b) + 0x8000u) & 0xFFFF0000u);
}
__device__ __forceinline__ float b2f_lo(unsigned int u) { return __uint_as_float(u << 16); }
__device__ __forceinline__ float b2f_hi(unsigned int u) { return __uint_as_float(u & 0xFFFF0000u); }

// ---------------------------------------------------------------------------
// GEMM body: C[M,N] = A[M,K] @ W[N,K]^T + bias. Tile 64(M)x128(N), Ktile=32,
// 512 threads / 8 waves. Double-buffered LDS, register prefetch.
// mode 0: fp32 out[r*EMB+n]
// mode 1: bf16 out[((b*16+h)*S+s)*64+d]   (head-split)
// mode 2: bf16 out[((b*16+h)*64+d)*S+s]   (v transposed per head)
// ---------------------------------------------------------------------------
template<int ABF16>
__device__ __forceinline__ void gemm_body(
    ushort (*As)[64 * 40], ushort (*Bs)[128 * 40],
    const void* __restrict__ A_, const float* __restrict__ W,
    const float* __restrict__ bias, void* __restrict__ out_,
    float scale, int mode)
{
    constexpr int K = EMB;
    constexpr int NT = K / 32;
    constexpr int LDP = 40;

    const int t    = threadIdx.x;
    const int lane = t & 63;
    const int wave = t >> 6;
    const int quad = lane >> 4;
    const int l15  = lane & 15;
    const int wm   = wave >> 2;          // 0..1
    const int wn   = wave & 3;           // 0..3
    const int m0   = blockIdx.x * 64;
    const int n0   = blockIdx.y * 128;

    const int rowA = t >> 3, ka = (t & 7) * 4;   // A: 64 rows x 32k, 4 u16/thr
    const int rowW = t >> 2, kw = (t & 3) * 8;   // W: 128 rows x 32k, 8 u16/thr

    const float*  Af  = (const float*)A_;
    const ushort* Ab  = (const ushort*)A_;
    const size_t aOff = (size_t)(m0 + rowA) * K + ka;
    const float*  Wp  = W + (size_t)(n0 + rowW) * K + kw;

    f32x4 acc[2][2];
#pragma unroll
    for (int mi = 0; mi < 2; ++mi)
#pragma unroll
        for (int ni = 0; ni < 2; ++ni) acc[mi][ni] = (f32x4){0.f, 0.f, 0.f, 0.f};

    uint2 ua;
    uint4 uw;
    if (ABF16) ua = *(const uint2*)(Ab + aOff);
    else {
        float4 f = *(const float4*)(Af + aOff);
        ua = make_uint2(pk2(f.x, f.y), pk2(f.z, f.w));
    }
    {
        float4 g0 = *(const float4*)(Wp);
        float4 g1 = *(const float4*)(Wp + 4);
        uw = make_uint4(pk2(g0.x,g0.y), pk2(g0.z,g0.w), pk2(g1.x,g1.y), pk2(g1.z,g1.w));
    }
    *(uint2*)&As[0][rowA * LDP + ka] = ua;
    *(uint4*)&Bs[0][rowW * LDP + kw] = uw;
    __syncthreads();

    for (int kt = 0; kt < NT; ++kt) {
        const int cur = kt & 1;
        if (kt + 1 < NT) {
            const int k0 = (kt + 1) * 32;
            if (ABF16) ua = *(const uint2*)(Ab + aOff + k0);
            else {
                float4 f = *(const float4*)(Af + aOff + k0);
                ua = make_uint2(pk2(f.x, f.y), pk2(f.z, f.w));
            }
            float4 g0 = *(const float4*)(Wp + k0);
            float4 g1 = *(const float4*)(Wp + k0 + 4);
            uw = make_uint4(pk2(g0.x,g0.y), pk2(g0.z,g0.w), pk2(g1.x,g1.y), pk2(g1.z,g1.w));
        }
        short8 af[2], bf[2];
#pragma unroll
        for (int mi = 0; mi < 2; ++mi)
            af[mi] = *(const short8*)&As[cur][(wm * 32 + mi * 16 + l15) * LDP + quad * 8];
#pragma unroll
        for (int ni = 0; ni < 2; ++ni)
            bf[ni] = *(const short8*)&Bs[cur][(wn * 32 + ni * 16 + l15) * LDP + quad * 8];
#pragma unroll
        for (int mi = 0; mi < 2; ++mi)
#pragma unroll
            for (int ni = 0; ni < 2; ++ni)
                acc[mi][ni] = __builtin_amdgcn_mfma_f32_16x16x32_bf16(
                    af[mi], bf[ni], acc[mi][ni], 0, 0, 0);
        if (kt + 1 < NT) {
            const int nxt = (kt + 1) & 1;
            *(uint2*)&As[nxt][rowA * LDP + ka] = ua;
            *(uint4*)&Bs[nxt][rowW * LDP + kw] = uw;
            __syncthreads();
        }
    }

#pragma unroll
    for (int mi = 0; mi < 2; ++mi)
#pragma unroll
        for (int ni = 0; ni < 2; ++ni) {
            const int col = n0 + wn * 32 + ni * 16 + l15;
            const float bc = bias[col];
#pragma unroll
            for (int r = 0; r < 4; ++r) {
                const int rg = m0 + wm * 32 + mi * 16 + quad * 4 + r;
                const float v = (acc[mi][ni][r] + bc) * scale;
                if (mode == 0) {
                    ((float*)out_)[(size_t)rg * EMB + col] = v;
                } else {
                    const int s  = rg >> 1;
                    const int bb = rg & 1;
                    const int h  = col >> 6;
                    const int d  = col & 63;
                    if (mode == 1)
                        ((ushort*)out_)[(((size_t)(bb * NHEAD + h)) * S_LEN + s) * HDIM + d] = f2b(v);
                    else
                        ((ushort*)out_)[(((size_t)(bb * NHEAD + h)) * HDIM + d) * S_LEN + s] = f2b(v);
                }
            }
        }
}

// Fused QKV projections: blockIdx.z in {0,1,2} selects q/k/v. 1536 blocks.
__global__ __launch_bounds__(512, 4)
void gemm_qkv(const float* __restrict__ qi, const float* __restrict__ ki,
              const float* __restrict__ vi,
              const float* __restrict__ qW, const float* __restrict__ kW,
              const float* __restrict__ vW,
              const float* __restrict__ qB, const float* __restrict__ kB,
              const float* __restrict__ vB,
              ushort* __restrict__ qO, ushort* __restrict__ kO,
              ushort* __restrict__ vO)
{
    __shared__ ushort As[2][64 * 40];
    __shared__ ushort Bs[2][128 * 40];
    const int z = blockIdx.z;
    const float* A    = (z == 0) ? qi : (z == 1) ? ki : vi;
    const float* W    = (z == 0) ? qW : (z == 1) ? kW : vW;
    const float* bias = (z == 0) ? qB : (z == 1) ? kB : vB;
    ushort* out       = (z == 0) ? qO : (z == 1) ? kO : vO;
    const float scale = (z == 0) ? 0.125f : 1.0f;
    const int   mode  = (z == 2) ? 2 : 1;
    gemm_body<0>(As, Bs, A, W, bias, out, scale, mode);
}

__global__ __launch_bounds__(512, 4)
void gemm_z(const ushort* __restrict__ A, const float* __restrict__ W,
            const float* __restrict__ bias, float* __restrict__ out)
{
    __shared__ ushort As[2][64 * 40];
    __shared__ ushort Bs[2][128 * 40];
    gemm_body<1>(As, Bs, A, W, bias, out, 1.0f, 0);
}

// ---------------------------------------------------------------------------
// Fused attention, v3. Block = 1024 threads / 16 waves = (16 q-rows, b),
// loops ALL 16 heads. 256 blocks = 1/CU, 16 waves/CU forced resident (a
// 1024-thr block requires <=128 regs/wave, and with pavg moved to LDS the
// live set fits -- R3/R5 showed pavg[4][16] in regs spills under a 128 cap).
// pavg accumulates in a bf16 LDS tile (owner-thread RMW, no races);
// attn_avg is written fp32 directly (no reduce kernel).
// Shift-softmax exp(s-8): shift-invariant, scores ~N(0,0.33), no overflow.
// 2 barriers per head (cross-head ordering safe: all pLds/redS/red2 reads of
// head h precede B2(h) or the reader's B1(h+1), writes for h+1 follow them).
// LDS: 65792 + 65536 + 1024 + 12288 = 144640 B.
// ---------------------------------------------------------------------------
#define PLD 2056   // 2048 + 8 pad (ushorts)
__global__ __launch_bounds__(1024, 4)
void attn_bf16(const ushort* __restrict__ qw, const ushort* __restrict__ kw,
               const ushort* __restrict__ vt, ushort* __restrict__ ao,
               float* __restrict__ attn_avg)
{
    __shared__ __align__(16) ushort pLds[16 * PLD];       // e (bf16), one head
    __shared__ __align__(16) ushort pavgLds[16 * 2048];   // bf16 sum of p over heads
    __shared__ __align__(16) float  redS[16 * 16];        // [wave][row] sum partials
    __shared__ __align__(16) float  red2[3 * 4 * 256];    // PV k-quarter partials

    const int t     = threadIdx.x;
    const int lane  = t & 63;
    const int wave  = t >> 6;              // 0..15
    const int quad  = lane >> 4;
    const int l15   = lane & 15;
    const int rbase = quad * 4;
    const int sq0   = blockIdx.x * 16;
    const int b     = blockIdx.y;
    const int ntile = wave & 3;            // PV d-tile
    const int kq    = wave >> 2;           // PV k-quarter

    // zero own pavg cells (row = wave, cols c*512 + lane*8); no barrier needed:
    // only this thread ever touches them.
#pragma unroll
    for (int c = 0; c < 4; ++c)
        *(uint4*)&pavgLds[wave * 2048 + c * 512 + lane * 8] = make_uint4(0u, 0u, 0u, 0u);

    for (int h = 0; h < NHEAD; ++h) {
        const int bh = b * NHEAD + h;
        const ushort* qbase = qw + ((size_t)bh * S_LEN + sq0) * HDIM;
        const ushort* kbse  = kw + (size_t)bh * S_LEN * HDIM;

        const short8 qf0 = *(const short8*)(qbase + l15 * HDIM + quad * 8);
        const short8 qf1 = *(const short8*)(qbase + l15 * HDIM + 32 + quad * 8);

        // ---- scores + exp + stage: wave owns cols [wave*128, wave*128+128) ----
        float s4[4] = {0.f, 0.f, 0.f, 0.f};
#pragma unroll
        for (int ti = 0; ti < 8; ++ti) {
            const int c0 = wave * 128 + ti * 16;
            const ushort* kr = kbse + (size_t)(c0 + l15) * HDIM;
            const short8 k0 = *(const short8*)(kr + quad * 8);
            const short8 k1 = *(const short8*)(kr + 32 + quad * 8);
            f32x4 a = (f32x4){0.f, 0.f, 0.f, 0.f};
            a = __builtin_amdgcn_mfma_f32_16x16x32_bf16(qf0, k0, a, 0, 0, 0);
            a = __builtin_amdgcn_mfma_f32_16x16x32_bf16(qf1, k1, a, 0, 0, 0);
#pragma unroll
            for (int r = 0; r < 4; ++r) {
                // exp(s - 8) = exp2(s*log2e - 8*log2e)
                const float e = exp2f(fmaf(a[r], 1.44269504f, -11.54156035f));
                s4[r] += e;
                pLds[(rbase + r) * PLD + c0 + l15] = f2bf(e);
            }
        }
#pragma unroll
        for (int off = 1; off < 16; off <<= 1)
#pragma unroll
            for (int r = 0; r < 4; ++r) s4[r] += __shfl_xor(s4[r], off, 16);
        if (l15 == 0)
#pragma unroll
            for (int r = 0; r < 4; ++r) redS[wave * 16 + rbase + r] = s4[r];
        __syncthreads();                                        // B1

        // row sums: rinv[] for this thread's quad rows (PV epilogue),
        // rr for row==wave (pavg phase). redS reads are wave-uniform -> bcast.
        f32x4 Sv = (f32x4){0.f, 0.f, 0.f, 0.f};
#pragma unroll
        for (int w = 0; w < 16; ++w) Sv += *(const f32x4*)&redS[w * 16 + rbase];
        float rinv[4];
#pragma unroll
        for (int r = 0; r < 4; ++r) rinv[r] = 1.0f / Sv[r];
        float sr = 0.f;
#pragma unroll
        for (int w = 0; w < 16; ++w) sr += redS[w * 16 + wave];
        const float rr = 1.0f / sr;

        // ---- pavg RMW in LDS: row = wave, cols c*512 + lane*8 (coalesced) ----
#pragma unroll
        for (int c = 0; c < 4; ++c) {
            const int idx = wave * 2048 + c * 512 + lane * 8;
            const uint4 e4 = *(const uint4*)&pLds[wave * PLD + c * 512 + lane * 8];
            uint4 a4 = *(const uint4*)&pavgLds[idx];
            a4.x = pk2f(fmaf(b2f_lo(e4.x), rr, b2f_lo(a4.x)),
                        fmaf(b2f_hi(e4.x), rr, b2f_hi(a4.x)));
            a4.y = pk2f(fmaf(b2f_lo(e4.y), rr, b2f_lo(a4.y)),
                        fmaf(b2f_hi(e4.y), rr, b2f_hi(a4.y)));
            a4.z = pk2f(fmaf(b2f_lo(e4.z), rr, b2f_lo(a4.z)),
                        fmaf(b2f_hi(e4.z), rr, b2f_hi(a4.z)));
            a4.w = pk2f(fmaf(b2f_lo(e4.w), rr, b2f_lo(a4.w)),
                        fmaf(b2f_hi(e4.w), rr, b2f_hi(a4.w)));
            *(uint4*)&pavgLds[idx] = a4;
        }

        // ---- PV: wave = (d-tile ntile, k-quarter kq of 512 keys) ----
        const ushort* vrow = vt + ((size_t)bh * HDIM + ntile * 16 + l15) * S_LEN + kq * 512;
        const ushort* prow = &pLds[l15 * PLD + kq * 512];
        f32x4 o0 = (f32x4){0.f, 0.f, 0.f, 0.f}, o1 = o0;
#pragma unroll
        for (int st = 0; st < 16; st += 2) {
            const short8 pa0 = *(const short8*)(prow + st * 32 + quad * 8);
            const short8 vb0 = *(const short8*)(vrow + st * 32 + quad * 8);
            o0 = __builtin_amdgcn_mfma_f32_16x16x32_bf16(pa0, vb0, o0, 0, 0, 0);
            const short8 pa1 = *(const short8*)(prow + (st + 1) * 32 + quad * 8);
            const short8 vb1 = *(const short8*)(vrow + (st + 1) * 32 + quad * 8);
            o1 = __builtin_amdgcn_mfma_f32_16x16x32_bf16(pa1, vb1, o1, 0, 0, 0);
        }
        const f32x4 o = o0 + o1;
        if (kq > 0) {
#pragma unroll
            for (int r = 0; r < 4; ++r)
                red2[(kq - 1) * 1024 + ntile * 256 + (rbase + r) * 16 + l15] = o[r];
        }
        __syncthreads();                                        // B2
        if (kq == 0) {
#pragma unroll
            for (int r = 0; r < 4; ++r) {
                const int ii = ntile * 256 + (rbase + r) * 16 + l15;
                const float val = (o[r] + red2[ii] + red2[1024 + ii] + red2[2048 + ii]) * rinv[r];
                const int s = sq0 + rbase + r;
                ao[((size_t)s * BATCH + b) * EMB + h * HDIM + ntile * 16 + l15] = f2b(val);
            }
        }
    }

    // ---- write attn_avg fp32 (row = wave; own cells, no barrier needed) ----
    const float inv16 = 0.0625f;
    float* dst = attn_avg + ((size_t)(b * S_LEN + sq0 + wave)) * S_LEN;
#pragma unroll
    for (int c = 0; c < 4; ++c) {
        const uint4 a4 = *(const uint4*)&pavgLds[wave * 2048 + c * 512 + lane * 8];
        float4 o0 = make_float4(b2f_lo(a4.x) * inv16, b2f_hi(a4.x) * inv16,
                                b2f_lo(a4.y) * inv16, b2f_hi(a4.y) * inv16);
        float4 o1 = make_float4(b2f_lo(a4.z) * inv16, b2f_hi(a4.z) * inv16,
                                b2f_lo(a4.w) * inv16, b2f_hi(a4.w) * inv16);
        *(float4*)(dst + c * 512 + lane * 8)     = o0;
        *(float4*)(dst + c * 512 + lane * 8 + 4) = o1;
    }
}

// ---------------------------------------------------------------------------
extern "C" void kernel_launch(void* const* d_in, const int* in_sizes, int n_in,
                              void* d_out, int out_size, void* d_ws, size_t ws_size,
                              hipStream_t stream)
{
    const float* query = (const float*)d_in[0];
    const float* key   = (const float*)d_in[1];
    const float* value = (const float*)d_in[2];
    const float* q_w   = (const float*)d_in[3];
    const float* q_b   = (const float*)d_in[4];
    const float* k_w   = (const float*)d_in[5];
    const float* k_b   = (const float*)d_in[6];
    const float* v_w   = (const float*)d_in[7];
    const float* v_b   = (const float*)d_in[8];
    const float* out_w = (const float*)d_in[9];
    const float* out_b = (const float*)d_in[10];

    float* Z        = (float*)d_out;                       // [S,B,E] fp32
    float* attn_avg = Z + (size_t)S_LEN * BATCH * EMB;     // [B,S,S] fp32

    const size_t QKV = (size_t)S_LEN * BATCH * EMB;        // 4,194,304
    ushort* q_ws  = (ushort*)d_ws;                         // bf16 [B*H][S][D]
    ushort* k_ws  = q_ws + QKV;                            // bf16 [B*H][S][D]
    ushort* vt_ws = k_ws + QKV;                            // bf16 [B*H][D][S]
    ushort* ao_ws = vt_ws + QKV;                           // bf16 [S][B][E]

    const dim3 blkG(512);
    const dim3 gq(64, 8, 3);                               // M/64 x N/128 x {q,k,v}
    gemm_qkv<<<gq, blkG, 0, stream>>>(query, key, value, q_w, k_w, v_w,
                                      q_b, k_b, v_b, q_ws, k_ws, vt_ws);

    const dim3 ga(S_LEN / 16, BATCH), blkA(1024);          // 256 blocks, 1/CU
    attn_bf16<<<ga, blkA, 0, stream>>>(q_ws, k_ws, vt_ws, ao_ws, attn_avg);

    const dim3 gz(64, 8);
    gemm_z<<<gz, blkG, 0, stream>>>(ao_ws, out_w, out_b, Z);
}